// Round 2
// baseline (684.131 us; speedup 1.0000x reference)
//
#include <hip/hip_runtime.h>

// Problem constants (from reference)
#define N_HEAD      8
#define D_K         32
#define CONCEPT_NUM 4096
#define MASK_NUM    3000
#define INPUT_DIM   256   // == N_HEAD * D_K

// ws layout (bytes):
//   qbuf : [3000][256] f32   @ 0          (3,072,000 B)
//   kT   : [8][32][4096] f32 @ 0x300000   (4,194,304 B)  (head, d, concept) -> concept contiguous
//   flags: [4096] i32        @ 0x700000   (16,384 B)
#define WS_KT_OFF    0x300000
#define WS_FLAGS_OFF 0x700000

// ---------------------------------------------------------------------------
// Projection GEMM: C = A @ W, A:[M][256], W:[256][256]
// mode 0: out[i*256 + j] = c              (qbuf, row-major)
// mode 1: out[(j>>5)*(32*4096) + (j&31)*4096 + i] = c   (kT layout)
// ---------------------------------------------------------------------------
__global__ __launch_bounds__(256) void proj_kernel(const float* __restrict__ A,
                                                   const float* __restrict__ W,
                                                   float* __restrict__ out,
                                                   int M, int mode) {
    __shared__ float Alds[64][33];
    __shared__ float Wlds[32][64];
    const int tid = threadIdx.x;
    const int m0 = blockIdx.x * 64;
    const int n0 = blockIdx.y * 64;
    const int tx = tid & 15;   // 16 col groups
    const int ty = tid >> 4;   // 16 row groups

    float acc[4][4] = {};

    for (int k0 = 0; k0 < 256; k0 += 32) {
        // A tile: 64 rows x 32 k
        {
            const int kk = tid & 31;
            const int r0 = (tid >> 5) * 8;
            #pragma unroll
            for (int i = 0; i < 8; ++i) {
                int m = m0 + r0 + i;
                Alds[r0 + i][kk] = (m < M) ? A[(size_t)m * 256 + k0 + kk] : 0.0f;
            }
        }
        // W tile: 32 k x 64 cols
        {
            const int c  = tid & 63;
            const int r0 = (tid >> 6) * 8;
            #pragma unroll
            for (int i = 0; i < 8; ++i) {
                Wlds[r0 + i][c] = W[(size_t)(k0 + r0 + i) * 256 + n0 + c];
            }
        }
        __syncthreads();
        #pragma unroll
        for (int kk = 0; kk < 32; ++kk) {
            float a[4], b[4];
            #pragma unroll
            for (int r = 0; r < 4; ++r) a[r] = Alds[ty * 4 + r][kk];
            #pragma unroll
            for (int c = 0; c < 4; ++c) b[c] = Wlds[kk][tx * 4 + c];
            #pragma unroll
            for (int r = 0; r < 4; ++r)
                #pragma unroll
                for (int c = 0; c < 4; ++c)
                    acc[r][c] += a[r] * b[c];
        }
        __syncthreads();
    }

    #pragma unroll
    for (int r = 0; r < 4; ++r) {
        int m = m0 + ty * 4 + r;
        if (m >= M) continue;
        #pragma unroll
        for (int c = 0; c < 4; ++c) {
            int j = n0 + tx * 4 + c;
            if (mode == 0)
                out[(size_t)m * 256 + j] = acc[r][c];
            else
                out[(size_t)(j >> 5) * (32 * 4096) + (size_t)(j & 31) * 4096 + m] = acc[r][c];
        }
    }
}

// ---------------------------------------------------------------------------
// Row-flag helpers (which concept rows receive attention output)
// ---------------------------------------------------------------------------
__global__ void zero_flags(int* __restrict__ flags) {
    flags[blockIdx.x * 256 + threadIdx.x] = 0;
}

__global__ void scatter_flags(const int* __restrict__ qt, int* __restrict__ flags) {
    int i = blockIdx.x * 256 + threadIdx.x;
    if (i < MASK_NUM) flags[qt[i]] = 1;
}

// ---------------------------------------------------------------------------
// Fused scores + softmax + scatter.  grid = (375 + 512, 8)
//   bx <  375 : 8 query rows x 4096 concepts, softmax, scatter-write
//   bx >= 375 : zero 8 concept rows (those not flagged)
// ---------------------------------------------------------------------------
__global__ __launch_bounds__(256) void attn_kernel(const float* __restrict__ qbuf,
                                                   const float* __restrict__ kT,
                                                   const int* __restrict__ qt,
                                                   const int* __restrict__ flags,
                                                   float* __restrict__ out) {
    const int h   = blockIdx.y;
    const int bx  = blockIdx.x;
    const int tid = threadIdx.x;

    if (bx >= 375) {
        // zero path: 512 blocks/head x 8 rows
        const int rb = (bx - 375) * 8;
        #pragma unroll
        for (int r = 0; r < 8; ++r) {
            const int row = rb + r;
            if (flags[row]) continue;
            float4* dst = (float4*)(out + (size_t)h * CONCEPT_NUM * CONCEPT_NUM +
                                    (size_t)row * CONCEPT_NUM);
            #pragma unroll
            for (int it = 0; it < 4; ++it)
                dst[it * 256 + tid] = make_float4(0.f, 0.f, 0.f, 0.f);
        }
        return;
    }

    __shared__ float qs[8][32];
    __shared__ int   qrow[8];
    __shared__ float wred[8][4];

    const int i0 = bx * 8;
    {
        int r = tid >> 5, d = tid & 31;
        // fold in 1/sqrt(D_K)
        qs[r][d] = qbuf[(size_t)(i0 + r) * 256 + h * 32 + d] * 0.17677669529663687f;
    }
    if (tid < 8) qrow[tid] = qt[i0 + tid];
    __syncthreads();

    const float* kbase = kT + (size_t)h * 32 * 4096;

    // scores: acc[r][j], thread owns concepts c = jgrp*1024 + tid*4 + {0..3}
    float acc[8][16] = {};
    for (int d = 0; d < 32; ++d) {
        const float4* kp = (const float4*)(kbase + (size_t)d * 4096);
        float4 kv[4];
        #pragma unroll
        for (int j = 0; j < 4; ++j) kv[j] = kp[j * 256 + tid];
        float qv[8];
        #pragma unroll
        for (int r = 0; r < 8; ++r) qv[r] = qs[r][d];
        #pragma unroll
        for (int r = 0; r < 8; ++r) {
            #pragma unroll
            for (int j = 0; j < 4; ++j) {
                acc[r][j * 4 + 0] += qv[r] * kv[j].x;
                acc[r][j * 4 + 1] += qv[r] * kv[j].y;
                acc[r][j * 4 + 2] += qv[r] * kv[j].z;
                acc[r][j * 4 + 3] += qv[r] * kv[j].w;
            }
        }
    }

    // exp + row sums (no max subtraction: |score| <~ 20, safe in f32)
    float lsum[8];
    #pragma unroll
    for (int r = 0; r < 8; ++r) {
        float s = 0.f;
        #pragma unroll
        for (int j = 0; j < 16; ++j) {
            float e = __expf(acc[r][j]);
            acc[r][j] = e;
            s += e;
        }
        lsum[r] = s;
    }

    const int lane = tid & 63;
    const int wid  = tid >> 6;
    #pragma unroll
    for (int r = 0; r < 8; ++r) {
        float s = lsum[r];
        #pragma unroll
        for (int off = 32; off >= 1; off >>= 1) s += __shfl_xor(s, off, 64);
        if (lane == 0) wred[r][wid] = s;
    }
    __syncthreads();

    float inv[8];
    #pragma unroll
    for (int r = 0; r < 8; ++r)
        inv[r] = 1.0f / (wred[r][0] + wred[r][1] + wred[r][2] + wred[r][3]);

    // normalized scatter-write
    #pragma unroll
    for (int r = 0; r < 8; ++r) {
        float4* dst = (float4*)(out + (size_t)h * CONCEPT_NUM * CONCEPT_NUM +
                                (size_t)qrow[r] * CONCEPT_NUM);
        #pragma unroll
        for (int j = 0; j < 4; ++j) {
            float4 v;
            v.x = acc[r][j * 4 + 0] * inv[r];
            v.y = acc[r][j * 4 + 1] * inv[r];
            v.z = acc[r][j * 4 + 2] * inv[r];
            v.w = acc[r][j * 4 + 3] * inv[r];
            dst[j * 256 + tid] = v;
        }
    }
}

// ---------------------------------------------------------------------------
extern "C" void kernel_launch(void* const* d_in, const int* in_sizes, int n_in,
                              void* d_out, int out_size, void* d_ws, size_t ws_size,
                              hipStream_t stream) {
    const int*   qt      = (const int*)d_in[0];
    const float* query   = (const float*)d_in[1];
    const float* key_emb = (const float*)d_in[2];
    const float* w_q     = (const float*)d_in[3];
    const float* w_k     = (const float*)d_in[4];
    float* out = (float*)d_out;

    char*  ws    = (char*)d_ws;
    float* qbuf  = (float*)ws;
    float* kT    = (float*)(ws + WS_KT_OFF);
    int*   flags = (int*)(ws + WS_FLAGS_OFF);

    zero_flags<<<16, 256, 0, stream>>>(flags);
    scatter_flags<<<(MASK_NUM + 255) / 256, 256, 0, stream>>>(qt, flags);

    // Q projection: 3000x256, tiles 64x64 -> grid (47, 4)
    proj_kernel<<<dim3(47, 4), 256, 0, stream>>>(query, w_q, qbuf, MASK_NUM, 0);
    // K projection: 4096x256 -> grid (64, 4), kT layout
    proj_kernel<<<dim3(64, 4), 256, 0, stream>>>(key_emb, w_k, kT, CONCEPT_NUM, 1);

    // fused attention + zero rows: 375 row-blocks + 512 zero-blocks per head
    attn_kernel<<<dim3(375 + 512, N_HEAD), 256, 0, stream>>>(qbuf, kT, qt, flags, out);
}